// Round 1
// baseline (131.167 us; speedup 1.0000x reference)
//
#include <hip/hip_runtime.h>
#include <math.h>

#define BB 16
#define TT 2048
#define FF 512

// Kernel 1: wt[b,t] = sigmoid(dot(x[b,t,:], w) + bias). One wave (64 lanes) per row.
__global__ __launch_bounds__(256) void wt_kernel(const float* __restrict__ x,
                                                 const float* __restrict__ w,
                                                 const float* __restrict__ bias,
                                                 float* __restrict__ wt) {
    int gid  = blockIdx.x * 256 + threadIdx.x;
    int row  = gid >> 6;    // [0, B*T)
    int lane = gid & 63;
    const float* xr = x + (size_t)row * FF + lane * 8;
    const float* wr = w + lane * 8;
    float4 a0 = *(const float4*)xr;
    float4 a1 = *(const float4*)(xr + 4);
    float4 w0 = *(const float4*)wr;
    float4 w1 = *(const float4*)(wr + 4);
    float s = a0.x * w0.x + a0.y * w0.y + a0.z * w0.z + a0.w * w0.w
            + a1.x * w1.x + a1.y * w1.y + a1.z * w1.z + a1.w * w1.w;
#pragma unroll
    for (int off = 32; off > 0; off >>= 1) s += __shfl_xor(s, off, 64);
    if (lane == 0) {
        float z = s + bias[0];
        wt[row] = 1.0f / (1.0f + expf(-z));
    }
}

// Kernel 2: per-batch valley detection + stream compaction of segment starts/ends.
// starts = [0, v1, ..., vk]; ends = [min(v1+2,T), ..., min(vk+2,T), T]; counts = k+1.
__global__ __launch_bounds__(256) void seg_kernel(const float* __restrict__ wt,
                                                  int* __restrict__ starts,
                                                  int* __restrict__ ends,
                                                  int* __restrict__ counts) {
    int b   = blockIdx.x;
    int tid = threadIdx.x;  // 0..255, 8 positions each
    __shared__ float sw[TT];
    __shared__ int   scan[256];
    const float* wrow = wt + b * TT;
    for (int i = tid; i < TT; i += 256) sw[i] = wrow[i];
    __syncthreads();

    int base = tid * 8;
    int flags = 0, cnt = 0;
#pragma unroll
    for (int k = 0; k < 8; ++k) {
        int t = base + k;
        bool v = (t > 0) && (t < TT - 1) && (sw[t] < sw[t - 1]) && (sw[t] < sw[t + 1]);
        if (v) { flags |= (1 << k); ++cnt; }
    }
    scan[tid] = cnt;
    __syncthreads();
    // Hillis-Steele inclusive scan over 256 per-thread counts
    for (int off = 1; off < 256; off <<= 1) {
        int add = (tid >= off) ? scan[tid - off] : 0;
        __syncthreads();
        scan[tid] += add;
        __syncthreads();
    }
    int total = scan[255];            // k = number of valleys
    int r = scan[tid] - cnt;          // exclusive rank of this thread's first valley
    int* sb = starts + b * TT;
    int* eb = ends + b * TT;
#pragma unroll
    for (int k = 0; k < 8; ++k) {
        if (flags & (1 << k)) {
            int t = base + k;
            sb[r + 1] = t;
            int e = t + 2; if (e > TT) e = TT;
            eb[r] = e;
            ++r;
        }
    }
    if (tid == 0) {
        sb[0] = 0;
        eb[total] = TT;
        counts[b] = total + 1;
    }
}

// Kernel 3: one wave per output row (b,j): pooled = sum(wt*x over segment)/clamp(sum wt).
__global__ __launch_bounds__(256) void pool_kernel(const float* __restrict__ x,
                                                   const float* __restrict__ wt,
                                                   const int* __restrict__ starts,
                                                   const int* __restrict__ ends,
                                                   const int* __restrict__ counts,
                                                   float* __restrict__ out) {
    int gid  = blockIdx.x * 256 + threadIdx.x;
    int row  = gid >> 6;        // b*T + j
    int lane = gid & 63;
    int b = row >> 11;          // T = 2048
    int j = row & (TT - 1);
    float4 acc0 = make_float4(0.f, 0.f, 0.f, 0.f);
    float4 acc1 = make_float4(0.f, 0.f, 0.f, 0.f);
    if (j < counts[b]) {
        int s = starts[row], e = ends[row];
        const float* xb   = x + (size_t)b * TT * FF + lane * 8;
        const float* wrow = wt + b * TT;
        float den = 0.f;
        for (int t = s; t < e; ++t) {
            float wv = wrow[t];
            const float4* p = (const float4*)(xb + (size_t)t * FF);
            float4 v0 = p[0], v1 = p[1];
            acc0.x += wv * v0.x; acc0.y += wv * v0.y;
            acc0.z += wv * v0.z; acc0.w += wv * v0.w;
            acc1.x += wv * v1.x; acc1.y += wv * v1.y;
            acc1.z += wv * v1.z; acc1.w += wv * v1.w;
            den += wv;
        }
        float inv = 1.0f / fmaxf(den, 1e-6f);
        acc0.x *= inv; acc0.y *= inv; acc0.z *= inv; acc0.w *= inv;
        acc1.x *= inv; acc1.y *= inv; acc1.z *= inv; acc1.w *= inv;
    }
    float* orow = out + (size_t)row * FF + lane * 8;
    *(float4*)orow = acc0;
    *(float4*)(orow + 4) = acc1;
}

// Kernel 4: new_mask[b,t] = t < int(min(seq,T)/min(seq0,T) * max(counts)); written as 0/1 f32.
__global__ __launch_bounds__(256) void mask_kernel(const int* __restrict__ counts,
                                                   const int* __restrict__ seq_len,
                                                   float* __restrict__ mask_out) {
    int idx = blockIdx.x * 256 + threadIdx.x;  // [0, B*T)
    int b = idx >> 11;
    int t = idx & (TT - 1);
    int maxc = 0;
#pragma unroll
    for (int i = 0; i < BB; ++i) maxc = max(maxc, counts[i]);
    int len_b = min(seq_len[b], TT);
    int len0  = min(seq_len[0], TT);
    int nl = (int)((float)len_b / (float)len0 * (float)maxc);
    mask_out[idx] = (t < nl) ? 1.0f : 0.0f;
}

extern "C" void kernel_launch(void* const* d_in, const int* in_sizes, int n_in,
                              void* d_out, int out_size, void* d_ws, size_t ws_size,
                              hipStream_t stream) {
    const float* x       = (const float*)d_in[0];
    const float* w_aggr  = (const float*)d_in[1];
    const float* b_aggr  = (const float*)d_in[2];
    const int*   seq_len = (const int*)d_in[3];

    float* pooled = (float*)d_out;
    float* mask   = (float*)d_out + (size_t)BB * TT * FF;

    // workspace: wt [B*T] f32 | starts [B*T] i32 | ends [B*T] i32 | counts [B] i32
    float* wt    = (float*)d_ws;
    int* starts  = (int*)((char*)d_ws + (size_t)BB * TT * 4);
    int* ends    = starts + BB * TT;
    int* counts  = ends + BB * TT;

    const int rows = BB * TT;                 // 32768
    wt_kernel<<<rows / 4, 256, 0, stream>>>(x, w_aggr, b_aggr, wt);
    seg_kernel<<<BB, 256, 0, stream>>>(wt, starts, ends, counts);
    pool_kernel<<<rows / 4, 256, 0, stream>>>(x, wt, starts, ends, counts, pooled);
    mask_kernel<<<rows / 256, 256, 0, stream>>>(counts, seq_len, mask);
}

// Round 2
// 128.717 us; speedup vs baseline: 1.0190x; 1.0190x over previous
//
#include <hip/hip_runtime.h>
#include <math.h>

#define BB 16
#define TT 2048
#define FF 512
#define POOL_BLOCKS ((BB * TT) / 4)   // 8192 blocks, 4 waves each, 1 wave per output row
#define MASK_BLOCKS ((BB * TT) / 256) // 128 blocks for the mask tail

// Kernel 1: wt[b,t] = sigmoid(dot(x[b,t,:], w) + bias). One wave (64 lanes) per row.
__global__ __launch_bounds__(256) void wt_kernel(const float* __restrict__ x,
                                                 const float* __restrict__ w,
                                                 const float* __restrict__ bias,
                                                 float* __restrict__ wt) {
    int gid  = blockIdx.x * 256 + threadIdx.x;
    int row  = gid >> 6;    // [0, B*T)
    int lane = gid & 63;
    const float* xr = x + (size_t)row * FF + lane * 8;
    const float* wr = w + lane * 8;
    float4 a0 = *(const float4*)xr;
    float4 a1 = *(const float4*)(xr + 4);
    float4 w0 = *(const float4*)wr;
    float4 w1 = *(const float4*)(wr + 4);
    float s = a0.x * w0.x + a0.y * w0.y + a0.z * w0.z + a0.w * w0.w
            + a1.x * w1.x + a1.y * w1.y + a1.z * w1.z + a1.w * w1.w;
#pragma unroll
    for (int off = 32; off > 0; off >>= 1) s += __shfl_xor(s, off, 64);
    if (lane == 0) {
        float z = s + bias[0];
        wt[row] = 1.0f / (1.0f + expf(-z));
    }
}

// Kernel 2: one WAVE per batch. Valley detect + wave-scan compaction, no barriers.
// starts = [0, v1, ..., vk]; ends = [v1+2, ..., vk+2, T] (vk+2 <= T always); counts = k+1.
__global__ __launch_bounds__(64) void seg_kernel(const float* __restrict__ wt,
                                                 int* __restrict__ starts,
                                                 int* __restrict__ ends,
                                                 int* __restrict__ counts) {
    int b    = blockIdx.x;
    int lane = threadIdx.x;              // 0..63, 32 consecutive positions each
    const float* wrow = wt + b * TT;
    float v[32];
    const float4* p = (const float4*)(wrow + lane * 32);
#pragma unroll
    for (int k = 0; k < 8; ++k) {
        float4 f = p[k];
        v[4*k] = f.x; v[4*k+1] = f.y; v[4*k+2] = f.z; v[4*k+3] = f.w;
    }
    float left  = __shfl_up(v[31], 1, 64);   // wt[lane*32 - 1] (lane 0: t=0 guarded out)
    float right = __shfl_down(v[0], 1, 64);  // wt[lane*32 + 32] (lane 63: t=2047 guarded out)
    unsigned int flags = 0;
#pragma unroll
    for (int k = 0; k < 32; ++k) {
        int t = lane * 32 + k;
        float prev = (k == 0)  ? left  : v[k - 1];
        float next = (k == 31) ? right : v[k + 1];
        bool val = (t > 0) && (t < TT - 1) && (v[k] < prev) && (v[k] < next);
        if (val) flags |= (1u << k);
    }
    int cnt = __popc(flags);
    // inclusive wave scan of cnt via shuffles
    int inc = cnt;
#pragma unroll
    for (int off = 1; off < 64; off <<= 1) {
        int y = __shfl_up(inc, off, 64);
        if (lane >= off) inc += y;
    }
    int total = __shfl(inc, 63, 64);
    int r = inc - cnt;                   // exclusive rank
    int* sb = starts + b * TT;
    int* eb = ends + b * TT;
    unsigned int f = flags;
    while (f) {
        int k = __ffs(f) - 1;
        f &= f - 1;
        int t = lane * 32 + k;
        sb[r + 1] = t;
        eb[r] = t + 2;                   // t <= 2046 -> t+2 <= 2048 = TT, no clip needed
        ++r;
    }
    if (lane == 0) {
        sb[0] = 0;
        eb[total] = TT;
        counts[b] = total + 1;
    }
}

// Kernel 3: fused pool + mask.
// Blocks [0, POOL_BLOCKS): one wave per output row (b,j): sum(wt*x)/clamp(sum wt).
// Blocks [POOL_BLOCKS, +MASK_BLOCKS): new_mask as 0/1 f32.
__global__ __launch_bounds__(256) void pool_mask_kernel(const float* __restrict__ x,
                                                        const float* __restrict__ wt,
                                                        const int* __restrict__ starts,
                                                        const int* __restrict__ ends,
                                                        const int* __restrict__ counts,
                                                        const int* __restrict__ seq_len,
                                                        float* __restrict__ out,
                                                        float* __restrict__ mask_out) {
    int blk = blockIdx.x;
    if (blk >= POOL_BLOCKS) {
        int idx = (blk - POOL_BLOCKS) * 256 + threadIdx.x;   // [0, B*T)
        int b = idx >> 11;
        int t = idx & (TT - 1);
        int maxc = 0;
#pragma unroll
        for (int i = 0; i < BB; ++i) maxc = max(maxc, counts[i]);
        int len_b = min(seq_len[b], TT);
        int len0  = min(seq_len[0], TT);
        int nl = (int)((float)len_b / (float)len0 * (float)maxc);
        mask_out[idx] = (t < nl) ? 1.0f : 0.0f;
        return;
    }
    int gid  = blk * 256 + threadIdx.x;
    int row  = gid >> 6;        // b*T + j
    int lane = gid & 63;
    int b = row >> 11;          // T = 2048
    int j = row & (TT - 1);
    float4 acc0 = make_float4(0.f, 0.f, 0.f, 0.f);
    float4 acc1 = make_float4(0.f, 0.f, 0.f, 0.f);
    if (j < counts[b]) {
        int s = starts[row], e = ends[row];
        const float* xb   = x + (size_t)b * TT * FF + lane * 8;
        const float* wrow = wt + b * TT;
        float den = 0.f;
        for (int t = s; t < e; ++t) {
            float wv = wrow[t];
            const float4* p = (const float4*)(xb + (size_t)t * FF);
            float4 v0 = p[0], v1 = p[1];
            acc0.x += wv * v0.x; acc0.y += wv * v0.y;
            acc0.z += wv * v0.z; acc0.w += wv * v0.w;
            acc1.x += wv * v1.x; acc1.y += wv * v1.y;
            acc1.z += wv * v1.z; acc1.w += wv * v1.w;
            den += wv;
        }
        float inv = 1.0f / fmaxf(den, 1e-6f);
        acc0.x *= inv; acc0.y *= inv; acc0.z *= inv; acc0.w *= inv;
        acc1.x *= inv; acc1.y *= inv; acc1.z *= inv; acc1.w *= inv;
    }
    float* orow = out + (size_t)row * FF + lane * 8;
    *(float4*)orow = acc0;
    *(float4*)(orow + 4) = acc1;
}

extern "C" void kernel_launch(void* const* d_in, const int* in_sizes, int n_in,
                              void* d_out, int out_size, void* d_ws, size_t ws_size,
                              hipStream_t stream) {
    const float* x       = (const float*)d_in[0];
    const float* w_aggr  = (const float*)d_in[1];
    const float* b_aggr  = (const float*)d_in[2];
    const int*   seq_len = (const int*)d_in[3];

    float* pooled = (float*)d_out;
    float* mask   = (float*)d_out + (size_t)BB * TT * FF;

    // workspace: wt [B*T] f32 | starts [B*T] i32 | ends [B*T] i32 | counts [B] i32
    float* wt    = (float*)d_ws;
    int* starts  = (int*)((char*)d_ws + (size_t)BB * TT * 4);
    int* ends    = starts + BB * TT;
    int* counts  = ends + BB * TT;

    const int rows = BB * TT;                 // 32768
    wt_kernel<<<rows / 4, 256, 0, stream>>>(x, w_aggr, b_aggr, wt);
    seg_kernel<<<BB, 64, 0, stream>>>(wt, starts, ends, counts);
    pool_mask_kernel<<<POOL_BLOCKS + MASK_BLOCKS, 256, 0, stream>>>(
        x, wt, starts, ends, counts, seq_len, pooled, mask);
}